// Round 1
// baseline (4342.587 us; speedup 1.0000x reference)
//
#include <hip/hip_runtime.h>
#include <math.h>

#define BB 512
#define SS 2048
#define DD 19
#define HH 40
#define G4 160        // 4*H
#define CHUNK 128
#define NCHUNK (SS / CHUNK)   // 16
#define RSTR 41       // ring stride in floats: gcd(41,32)=1 -> conflict-free
#define XSTR 20       // x row stride in LDS (16B aligned rows)

__device__ __forceinline__ float fast_sigmoid(float x) {
    return 1.0f / (1.0f + __expf(-x));
}
__device__ __forceinline__ float fast_tanh(float x) {
    // 1 - 2/(exp(2x)+1); saturates correctly for |x| large (inf -> 1, 0 -> -1)
    return 1.0f - 2.0f / (__expf(2.0f * x) + 1.0f);
}

__global__ void lstm_fused(const float* __restrict__ x,
                           const float* __restrict__ W_ih,
                           const float* __restrict__ W_hh,
                           const float* __restrict__ b_ih,
                           const float* __restrict__ b_hh,
                           const float* __restrict__ ln_g,
                           const float* __restrict__ ln_b,
                           const float* __restrict__ W1,
                           const float* __restrict__ b1,
                           const float* __restrict__ W2,
                           const float* __restrict__ b2,
                           const float* __restrict__ Wo,
                           const float* __restrict__ bo,
                           const float* __restrict__ log_thr,
                           float* __restrict__ out) {
    __shared__ float s_ring[CHUNK * RSTR];   // h per step of chunk; reused for res1
    __shared__ float s_x[CHUNK * XSTR];      // staged x chunk
    __shared__ float s_W1[HH * HH];
    __shared__ float s_W2[HH * HH];
    __shared__ float s_b1[HH], s_b2[HH], s_lng[HH], s_lnb[HH], s_Wo[HH];
    __shared__ float s_h[HH];
    __shared__ float s_gates[G4];
    __shared__ float s_part[256];

    const int tid = threadIdx.x;
    const int b = blockIdx.x;

    // ---- stage small weights into LDS ----
    for (int i = tid; i < HH * HH; i += 256) {
        s_W1[i] = W1[i];
        s_W2[i] = W2[i];
    }
    if (tid < HH) {
        s_b1[tid] = b1[tid];
        s_b2[tid] = b2[tid];
        s_lng[tid] = ln_g[tid];
        s_lnb[tid] = ln_b[tid];
        s_Wo[tid] = Wo[tid];
        s_h[tid] = 0.0f;
    }

    // ---- per-thread gate weights in registers ----
    float wih[DD];
    float whh[HH];
    float bsum = 0.0f;
    if (tid < G4) {
#pragma unroll
        for (int d = 0; d < DD; ++d) wih[d] = W_ih[tid * DD + d];
#pragma unroll
        for (int k = 0; k < HH; ++k) whh[k] = W_hh[tid * HH + k];
        bsum = b_ih[tid] + b_hh[tid];
    }

    float c = 0.0f;      // cell state (tid < 40)
    float hlast = 0.0f;  // final hidden (tid < 40)
    const float bo0 = bo[0];
    const float thr = expf(log_thr[0]);

    const size_t xbase = (size_t)b * SS * DD;

    for (int ch = 0; ch < NCHUNK; ++ch) {
        __syncthreads();  // ring + s_x free (consumer of prev chunk done)

        // ---- stage x chunk (coalesced) ----
        {
            const float* xp = x + xbase + (size_t)ch * CHUNK * DD;
            for (int i = tid; i < CHUNK * DD; i += 256) {
                int st = i / DD;
                int d = i - st * DD;
                s_x[st * XSTR + d] = xp[i];
            }
        }
        __syncthreads();

        // ---- producer: CHUNK recurrent steps ----
        for (int t = 0; t < CHUNK; ++t) {
            if (tid < G4) {
                float a0 = bsum, a1 = 0.0f, a2 = 0.0f, a3 = 0.0f;
                const float* xs = &s_x[t * XSTR];
#pragma unroll
                for (int d = 0; d < DD; ++d) {
                    float p = fmaf(xs[d], wih[d], 0.0f);
                    if ((d & 3) == 0) a0 += p;
                    else if ((d & 3) == 1) a1 += p;
                    else if ((d & 3) == 2) a2 += p;
                    else a3 += p;
                }
#pragma unroll
                for (int k = 0; k < HH; ++k) {
                    float p = s_h[k] * whh[k];
                    if ((k & 3) == 0) a0 += p;
                    else if ((k & 3) == 1) a1 += p;
                    else if ((k & 3) == 2) a2 += p;
                    else a3 += p;
                }
                float acc = (a0 + a1) + (a2 + a3);
                float a = (tid >= 2 * HH && tid < 3 * HH) ? fast_tanh(acc)
                                                          : fast_sigmoid(acc);
                s_gates[tid] = a;
            }
            __syncthreads();
            if (tid < HH) {
                float gi = s_gates[tid];
                float gf = s_gates[HH + tid];
                float gg = s_gates[2 * HH + tid];
                float go = s_gates[3 * HH + tid];
                c = fmaf(gf, c, gi * gg);
                float hv = go * fast_tanh(c);
                hlast = hv;
                s_h[tid] = hv;
                s_ring[t * RSTR + tid] = hv;
            }
            __syncthreads();
        }

        // ---- consumer: LN + MLP + head for CHUNK steps ----
        const int step = tid & (CHUNK - 1);
        const int half = tid >> 7;  // waves 0-1: half 0; waves 2-3: half 1
        const float* ringrow = &s_ring[step * RSTR];

        float v[HH];
#pragma unroll
        for (int k = 0; k < HH; ++k) v[k] = ringrow[k];

        float m0 = 0.f, m1 = 0.f, m2 = 0.f, m3 = 0.f;
#pragma unroll
        for (int k = 0; k < HH; ++k) {
            if ((k & 3) == 0) m0 += v[k];
            else if ((k & 3) == 1) m1 += v[k];
            else if ((k & 3) == 2) m2 += v[k];
            else m3 += v[k];
        }
        float mu = ((m0 + m1) + (m2 + m3)) * (1.0f / HH);
        float q0 = 0.f, q1 = 0.f, q2 = 0.f, q3 = 0.f;
#pragma unroll
        for (int k = 0; k < HH; ++k) {
            float d0 = v[k] - mu;
            float p = d0 * d0;
            if ((k & 3) == 0) q0 += p;
            else if ((k & 3) == 1) q1 += p;
            else if ((k & 3) == 2) q2 += p;
            else q3 += p;
        }
        float var = ((q0 + q1) + (q2 + q3)) * (1.0f / HH);
        float inv = 1.0f / sqrtf(var + 1e-5f);
#pragma unroll
        for (int k = 0; k < HH; ++k) {
            v[k] = (v[k] - mu) * inv * s_lng[k] + s_lnb[k];  // v := ln
        }

        // partial sum of sigmoid(ln)*Wo (computed once, by half 0)
        float sigWo = 0.0f;
        if (half == 0) {
#pragma unroll
            for (int k = 0; k < HH; ++k) {
                sigWo = fmaf(fast_sigmoid(v[k]), s_Wo[k], sigWo);
            }
        }
        __syncthreads();  // all h reads done -> ring reusable for res1

        // res1 = tanh(ln @ W1^T + b1), own half of rows
        for (int jj = 0; jj < HH / 2; ++jj) {
            int j = half * (HH / 2) + jj;
            const float* wrow = &s_W1[j * HH];
            float a0 = 0.f, a1 = 0.f, a2 = 0.f, a3 = 0.f;
#pragma unroll
            for (int k = 0; k < HH; ++k) {
                float p = wrow[k] * v[k];
                if ((k & 3) == 0) a0 += p;
                else if ((k & 3) == 1) a1 += p;
                else if ((k & 3) == 2) a2 += p;
                else a3 += p;
            }
            float r = fast_tanh(((a0 + a1) + (a2 + a3)) + s_b1[j]);
            s_ring[step * RSTR + j] = r;
        }
        __syncthreads();

        float rr[HH];
#pragma unroll
        for (int k = 0; k < HH; ++k) rr[k] = ringrow[k];

        float part = sigWo;
        for (int jj = 0; jj < HH / 2; ++jj) {
            int j = half * (HH / 2) + jj;
            const float* wrow = &s_W2[j * HH];
            float a0 = 0.f, a1 = 0.f, a2 = 0.f, a3 = 0.f;
#pragma unroll
            for (int k = 0; k < HH; ++k) {
                float p = wrow[k] * rr[k];
                if ((k & 3) == 0) a0 += p;
                else if ((k & 3) == 1) a1 += p;
                else if ((k & 3) == 2) a2 += p;
                else a3 += p;
            }
            float r2 = fast_tanh(((a0 + a1) + (a2 + a3)) + s_b2[j]);
            part = fmaf(r2, s_Wo[j], part);
        }
        s_part[tid] = part;
        __syncthreads();
        if (tid < CHUNK) {
            float tot = s_part[tid] + s_part[tid + CHUNK] + bo0;
            float raw = fast_tanh(tot);
            float sg = (fabsf(raw) >= thr) ? raw : 0.0f;
            out[(size_t)b * SS + (size_t)ch * CHUNK + tid] = sg;
        }
    }

    // ---- final states + threshold scalar ----
    if (tid < HH) {
        out[(size_t)BB * SS + (size_t)b * HH + tid] = hlast;
        out[(size_t)BB * SS + (size_t)BB * HH + (size_t)b * HH + tid] = c;
    }
    if (b == 0 && tid == 0) {
        out[(size_t)BB * SS + 2 * (size_t)BB * HH] = thr;
    }
}

extern "C" void kernel_launch(void* const* d_in, const int* in_sizes, int n_in,
                              void* d_out, int out_size, void* d_ws, size_t ws_size,
                              hipStream_t stream) {
    const float* x    = (const float*)d_in[0];
    const float* W_ih = (const float*)d_in[1];
    const float* W_hh = (const float*)d_in[2];
    const float* b_ih = (const float*)d_in[3];
    const float* b_hh = (const float*)d_in[4];
    const float* ln_g = (const float*)d_in[5];
    const float* ln_b = (const float*)d_in[6];
    const float* W1   = (const float*)d_in[7];
    const float* b1   = (const float*)d_in[8];
    const float* W2   = (const float*)d_in[9];
    const float* b2   = (const float*)d_in[10];
    const float* Wo   = (const float*)d_in[11];
    const float* bo   = (const float*)d_in[12];
    const float* lt   = (const float*)d_in[13];
    float* out = (float*)d_out;

    lstm_fused<<<dim3(BB), dim3(256), 0, stream>>>(
        x, W_ih, W_hh, b_ih, b_hh, ln_g, ln_b, W1, b1, W2, b2, Wo, bo, lt, out);
}

// Round 2
// 1254.723 us; speedup vs baseline: 3.4610x; 3.4610x over previous
//
#include <hip/hip_runtime.h>
#include <math.h>

#define BB 512
#define SS 2048
#define DD 19
#define HH 40
#define G4 160        // 4*H
#define CHUNK 128
#define NCHUNK (SS / CHUNK)   // 16
#define RSTR 41       // ring stride in floats: gcd(41,32)=1 -> conflict-free
#define XSTR 20       // x row stride in LDS (80B, 16B-aligned rows)

__device__ __forceinline__ float fast_sigmoid(float x) {
    return 1.0f / (1.0f + __expf(-x));
}
__device__ __forceinline__ float fast_tanh(float x) {
    // 1 - 2/(exp(2x)+1); saturates correctly for |x| large
    return 1.0f - 2.0f / (__expf(2.0f * x) + 1.0f);
}

__global__ __launch_bounds__(256, 2)  // 2 waves/EU min -> VGPR cap 256, no spills; 2 blocks/CU
void lstm_fused(const float* __restrict__ x,
                const float* __restrict__ W_ih,
                const float* __restrict__ W_hh,
                const float* __restrict__ b_ih,
                const float* __restrict__ b_hh,
                const float* __restrict__ ln_g,
                const float* __restrict__ ln_b,
                const float* __restrict__ W1,
                const float* __restrict__ b1,
                const float* __restrict__ W2,
                const float* __restrict__ b2,
                const float* __restrict__ Wo,
                const float* __restrict__ bo,
                const float* __restrict__ log_thr,
                float* __restrict__ out) {
    __shared__ float s_ring[CHUNK * RSTR];   // h per step of chunk; reused for res1
    __shared__ float s_x[CHUNK * XSTR];      // staged x chunk
    __shared__ float s_W1[HH * HH];
    __shared__ float s_W2[HH * HH];
    __shared__ float s_b1[HH], s_b2[HH], s_lng[HH], s_lnb[HH], s_Wo[HH];
    __shared__ __align__(16) float s_h[HH];
    __shared__ float s_gates[G4];
    __shared__ float s_part[256];

    const int tid = threadIdx.x;
    const int b = blockIdx.x;

    // ---- stage small weights into LDS ----
    for (int i = tid; i < HH * HH; i += 256) {
        s_W1[i] = W1[i];
        s_W2[i] = W2[i];
    }
    if (tid < HH) {
        s_b1[tid] = b1[tid];
        s_b2[tid] = b2[tid];
        s_lng[tid] = ln_g[tid];
        s_lnb[tid] = ln_b[tid];
        s_Wo[tid] = Wo[tid];
        s_h[tid] = 0.0f;
    }

    // ---- per-thread gate weights in registers ----
    float wih[DD];
    float whh[HH];
    float bsum = 0.0f;
    if (tid < G4) {
#pragma unroll
        for (int d = 0; d < DD; ++d) wih[d] = W_ih[tid * DD + d];
#pragma unroll
        for (int k = 0; k < HH; ++k) whh[k] = W_hh[tid * HH + k];
        bsum = b_ih[tid] + b_hh[tid];
    }

    float c = 0.0f;      // cell state (tid < 40)
    float hlast = 0.0f;  // final hidden (tid < 40)
    const float bo0 = bo[0];
    const float thr = expf(log_thr[0]);

    const size_t xbase = (size_t)b * SS * DD;

    for (int ch = 0; ch < NCHUNK; ++ch) {
        __syncthreads();  // ring + s_x free (consumer of prev chunk done)

        // ---- stage x chunk (coalesced) ----
        {
            const float* xp = x + xbase + (size_t)ch * CHUNK * DD;
            for (int i = tid; i < CHUNK * DD; i += 256) {
                int st = i / DD;
                int d = i - st * DD;
                s_x[st * XSTR + d] = xp[i];
            }
        }
        __syncthreads();

        // ---- producer: CHUNK recurrent steps ----
        for (int t = 0; t < CHUNK; ++t) {
            if (tid < G4) {
                // vector-load x row (16 via float4, 3 scalar) and h (10x float4)
                float xv[DD];
                const float4* xs4 = (const float4*)&s_x[t * XSTR];
#pragma unroll
                for (int d4 = 0; d4 < 4; ++d4) {
                    float4 f = xs4[d4];
                    xv[4 * d4 + 0] = f.x; xv[4 * d4 + 1] = f.y;
                    xv[4 * d4 + 2] = f.z; xv[4 * d4 + 3] = f.w;
                }
                xv[16] = s_x[t * XSTR + 16];
                xv[17] = s_x[t * XSTR + 17];
                xv[18] = s_x[t * XSTR + 18];
                float hv[HH];
                const float4* h4 = (const float4*)s_h;
#pragma unroll
                for (int k4 = 0; k4 < HH / 4; ++k4) {
                    float4 f = h4[k4];
                    hv[4 * k4 + 0] = f.x; hv[4 * k4 + 1] = f.y;
                    hv[4 * k4 + 2] = f.z; hv[4 * k4 + 3] = f.w;
                }
                float a0 = bsum, a1 = 0.0f, a2 = 0.0f, a3 = 0.0f;
#pragma unroll
                for (int d = 0; d < DD; ++d) {
                    float p = xv[d] * wih[d];
                    if ((d & 3) == 0) a0 += p;
                    else if ((d & 3) == 1) a1 += p;
                    else if ((d & 3) == 2) a2 += p;
                    else a3 += p;
                }
#pragma unroll
                for (int k = 0; k < HH; ++k) {
                    float p = hv[k] * whh[k];
                    if ((k & 3) == 0) a0 += p;
                    else if ((k & 3) == 1) a1 += p;
                    else if ((k & 3) == 2) a2 += p;
                    else a3 += p;
                }
                float acc = (a0 + a1) + (a2 + a3);
                float a = (tid >= 2 * HH && tid < 3 * HH) ? fast_tanh(acc)
                                                          : fast_sigmoid(acc);
                s_gates[tid] = a;
            }
            __syncthreads();
            if (tid < HH) {
                float gi = s_gates[tid];
                float gf = s_gates[HH + tid];
                float gg = s_gates[2 * HH + tid];
                float go = s_gates[3 * HH + tid];
                c = fmaf(gf, c, gi * gg);
                float hv = go * fast_tanh(c);
                hlast = hv;
                s_h[tid] = hv;
                s_ring[t * RSTR + tid] = hv;
            }
            __syncthreads();
        }

        // ---- consumer: LN + MLP + head for CHUNK steps ----
        const int step = tid & (CHUNK - 1);
        const int half = tid >> 7;  // waves 0-1: half 0; waves 2-3: half 1
        const float* ringrow = &s_ring[step * RSTR];

        float v[HH];
#pragma unroll
        for (int k = 0; k < HH; ++k) v[k] = ringrow[k];

        float m0 = 0.f, m1 = 0.f, m2 = 0.f, m3 = 0.f;
#pragma unroll
        for (int k = 0; k < HH; ++k) {
            if ((k & 3) == 0) m0 += v[k];
            else if ((k & 3) == 1) m1 += v[k];
            else if ((k & 3) == 2) m2 += v[k];
            else m3 += v[k];
        }
        float mu = ((m0 + m1) + (m2 + m3)) * (1.0f / HH);
        float q0 = 0.f, q1 = 0.f, q2 = 0.f, q3 = 0.f;
#pragma unroll
        for (int k = 0; k < HH; ++k) {
            float d0 = v[k] - mu;
            float p = d0 * d0;
            if ((k & 3) == 0) q0 += p;
            else if ((k & 3) == 1) q1 += p;
            else if ((k & 3) == 2) q2 += p;
            else q3 += p;
        }
        float var = ((q0 + q1) + (q2 + q3)) * (1.0f / HH);
        float inv = 1.0f / sqrtf(var + 1e-5f);
#pragma unroll
        for (int k = 0; k < HH; ++k) {
            v[k] = (v[k] - mu) * inv * s_lng[k] + s_lnb[k];  // v := ln
        }

        // partial sum of sigmoid(ln)*Wo (computed once, by half 0)
        float sigWo = 0.0f;
        if (half == 0) {
#pragma unroll
            for (int k = 0; k < HH; ++k) {
                sigWo = fmaf(fast_sigmoid(v[k]), s_Wo[k], sigWo);
            }
        }
        __syncthreads();  // all h reads done -> ring reusable for res1

        // res1 = tanh(ln @ W1^T + b1), own half of rows
        for (int jj = 0; jj < HH / 2; ++jj) {
            int j = half * (HH / 2) + jj;
            const float* wrow = &s_W1[j * HH];
            float a0 = 0.f, a1 = 0.f, a2 = 0.f, a3 = 0.f;
#pragma unroll
            for (int k = 0; k < HH; ++k) {
                float p = wrow[k] * v[k];
                if ((k & 3) == 0) a0 += p;
                else if ((k & 3) == 1) a1 += p;
                else if ((k & 3) == 2) a2 += p;
                else a3 += p;
            }
            float r = fast_tanh(((a0 + a1) + (a2 + a3)) + s_b1[j]);
            s_ring[step * RSTR + j] = r;
        }
        __syncthreads();

        float rr[HH];
#pragma unroll
        for (int k = 0; k < HH; ++k) rr[k] = ringrow[k];

        float part = sigWo;
        for (int jj = 0; jj < HH / 2; ++jj) {
            int j = half * (HH / 2) + jj;
            const float* wrow = &s_W2[j * HH];
            float a0 = 0.f, a1 = 0.f, a2 = 0.f, a3 = 0.f;
#pragma unroll
            for (int k = 0; k < HH; ++k) {
                float p = wrow[k] * rr[k];
                if ((k & 3) == 0) a0 += p;
                else if ((k & 3) == 1) a1 += p;
                else if ((k & 3) == 2) a2 += p;
                else a3 += p;
            }
            float r2 = fast_tanh(((a0 + a1) + (a2 + a3)) + s_b2[j]);
            part = fmaf(r2, s_Wo[j], part);
        }
        s_part[tid] = part;
        __syncthreads();
        if (tid < CHUNK) {
            float tot = s_part[tid] + s_part[tid + CHUNK] + bo0;
            float raw = fast_tanh(tot);
            float sg = (fabsf(raw) >= thr) ? raw : 0.0f;
            out[(size_t)b * SS + (size_t)ch * CHUNK + tid] = sg;
        }
    }

    // ---- final states + threshold scalar ----
    if (tid < HH) {
        out[(size_t)BB * SS + (size_t)b * HH + tid] = hlast;
        out[(size_t)BB * SS + (size_t)BB * HH + (size_t)b * HH + tid] = c;
    }
    if (b == 0 && tid == 0) {
        out[(size_t)BB * SS + 2 * (size_t)BB * HH] = thr;
    }
}

extern "C" void kernel_launch(void* const* d_in, const int* in_sizes, int n_in,
                              void* d_out, int out_size, void* d_ws, size_t ws_size,
                              hipStream_t stream) {
    const float* x    = (const float*)d_in[0];
    const float* W_ih = (const float*)d_in[1];
    const float* W_hh = (const float*)d_in[2];
    const float* b_ih = (const float*)d_in[3];
    const float* b_hh = (const float*)d_in[4];
    const float* ln_g = (const float*)d_in[5];
    const float* ln_b = (const float*)d_in[6];
    const float* W1   = (const float*)d_in[7];
    const float* b1   = (const float*)d_in[8];
    const float* W2   = (const float*)d_in[9];
    const float* b2   = (const float*)d_in[10];
    const float* Wo   = (const float*)d_in[11];
    const float* bo   = (const float*)d_in[12];
    const float* lt   = (const float*)d_in[13];
    float* out = (float*)d_out;

    lstm_fused<<<dim3(BB), dim3(256), 0, stream>>>(
        x, W_ih, W_hh, b_ih, b_hh, ln_g, ln_b, W1, b1, W2, b2, Wo, bo, lt, out);
}